// Round 8
// baseline (676.335 us; speedup 1.0000x reference)
//
#include <hip/hip_runtime.h>

// SNN classifier: h = x @ W1^T + b1 via f16 split-2 MFMA (3 terms), LIF scan.
//   x [128,25,12288] f32 ; W1 [2048,12288] ; Wo [2,2048]
// a = ah+al (in-register split after LDS read of raw fp32 x);
// w*128 = bh+bl (pre-converted by conv_w into B2);  h*128 = ah*bh+ah*bl+al*bh.
//
// GEMM: NON-persistent grid 416 = 13 mt x 8 nt x 4 ksp (mt slowest): the
// dispatch window holds ~8 mt chunks of x (97MB) + B2 (100MB) < 256MB L3
// (fixes r5-r7's contiguous-persistent L3 thrash: FETCH 1.24GB = 8x re-read
// of x). Each block: 256x256 tile, 96-kt K-chunk, writes partial to slot=ksp
// (exactly 4 slots). 512 thr, 8 waves 2Mx4N, wave-tile 128x64 of 32x32x16.
// Pipeline: A triple-buffered (2 tiles ahead), B double (1 ahead), counted
// s_waitcnt vmcnt(4) + raw s_barrier + sched_barrier(0) (r3-proven; never
// drains to 0 mid-loop). LDS = 3*32K A + 2*32K B = 160KB, 1 block/CU.
// LDS images [slot][row][16B] (A slot = 4-float k-group; B slots 0-3 hi /
// 4-7 lo): quarter-wave-contiguous ds_read_b128, conflict-free (r7: 0).
// LIF: phase 1 (256 blocks) sums 4 slots + Wo partials; phase 2 scans out.

#define T_STEPS 25
#define B_SZ    128
#define F_SZ    12288
#define HID_SZ  2048
#define KT      384
#define M_PAD   3328           // 13 * 256
#define PART_STRIDE ((size_t)M_PAD * HID_SZ)

typedef __attribute__((ext_vector_type(8))) _Float16 f16x8;
typedef __attribute__((ext_vector_type(4))) float f32x4;
typedef __attribute__((ext_vector_type(16))) float f32x16;

__device__ __forceinline__ void g2l16(const void* g, void* l) {
  __builtin_amdgcn_global_load_lds(
      (const __attribute__((address_space(1))) void*)g,
      (__attribute__((address_space(3))) void*)l, 16, 0, 0);
}

// 8 fp32 -> f16 hi (RNE) + f16 residual lo (validated r6/r7: absmax 0)
__device__ __forceinline__ void split8(f32x4 v0, f32x4 v1, f16x8& hi, f16x8& lo) {
#pragma unroll
  for (int j = 0; j < 4; ++j) {
    _Float16 h = (_Float16)v0[j];
    hi[j] = h;
    lo[j] = (_Float16)(v0[j] - (float)h);
    _Float16 h2 = (_Float16)v1[j];
    hi[4 + j] = h2;
    lo[4 + j] = (_Float16)(v1[j] - (float)h2);
  }
}

// ---- conv_w: W1*128 -> B2 [nt 0..7][ks][slot][col][16B] (hi 0-3, lo 4-7) --
__global__ __launch_bounds__(256) void conv_w_kernel(
    const float* __restrict__ W1, char* __restrict__ B2) {
  const int total = 8 * KT * 256 * 4;
  for (int i = blockIdx.x * 256 + threadIdx.x; i < total; i += gridDim.x * 256) {
    const int s = i & 3;
    const int r = (i >> 2) & 255;
    const int rest = i >> 10;            // nt*KT + ks
    const int ks = rest % KT;
    const int nt = rest / KT;
    const float* src = W1 + ((size_t)(nt * 256 + r)) * F_SZ + ks * 32 + s * 8;
    float4 v0 = *(const float4*)src;
    float4 v1 = *(const float4*)(src + 4);
    float vf[8] = {v0.x, v0.y, v0.z, v0.w, v1.x, v1.y, v1.z, v1.w};
    f16x8 hi, lo;
#pragma unroll
    for (int j = 0; j < 8; ++j) {
      float vs = vf[j] * 128.0f;         // scale keeps residual f16-normal
      _Float16 h = (_Float16)vs;
      hi[j] = h;
      lo[j] = (_Float16)(vs - (float)h);
    }
    char* chunk = B2 + (size_t)rest * 32768;
    *(f16x8*)(chunk + s * 4096 + r * 16) = hi;
    *(f16x8*)(chunk + (s + 4) * 4096 + r * 16) = lo;
  }
}

// ---- tiled MFMA GEMM: 416 blocks, 96-kt chunks, 2-deep A pipeline ----------
__global__ __launch_bounds__(512, 1) void gemm_tile_kernel(
    const float* __restrict__ x, const char* __restrict__ B2,
    float* __restrict__ parts) {
  // LDS: A bufs x3 @ 0/32K/64K ; B bufs x2 @ 96K/128K  (160KB total)
  __shared__ __align__(16) char lds[163840];
  const int tid = threadIdx.x;
  const int l = tid & 63;
  const int w = tid >> 6;
  const int wm = w >> 2;       // 0..1: rows wm*128
  const int wn = w & 3;        // 0..3: cols wn*64
  const int lhalf = l >> 5;

  const int bid = blockIdx.x;          // mt slowest for dispatch-window locality
  const int mt = bid >> 5;             // 0..12
  const int nt = (bid >> 2) & 7;       // 0..7
  const int ksp = bid & 3;             // 0..3
  const int kt0 = ksp * 96;
  const int ktN = kt0 + 96;

  const int arow = (wm * 128 + (l & 31)) * 16;  // A row byte base in image
  const int brow = (wn * 64 + (l & 31)) * 16;   // B col byte base

  // A: one source row per thread-pair (slot parity = tid>>8)
  int m = mt * 256 + (tid & 255);
  if (m > 3199) m = 3199;              // pad rows read row 3199 (harmless)
  const char* aRow = (const char*)(x +
      ((size_t)((m & 127) * T_STEPS + (m >> 7))) * F_SZ) + ((tid >> 8) << 4);
  const char* bBase = B2 + (size_t)nt * KT * 32768 + tid * 16;

#define STAGE_A(ktx, buf)                                                \
  do {                                                                   \
    char* d_ = (char*)lds + (buf) * 32768 + tid * 16;                    \
    const char* s_ = aRow + (ktx) * 128;                                 \
    g2l16(s_, d_);              g2l16(s_ + 32, d_ + 8192);               \
    g2l16(s_ + 64, d_ + 16384); g2l16(s_ + 96, d_ + 24576);              \
  } while (0)
#define STAGE_B(ktx, buf)                                                \
  do {                                                                   \
    char* d_ = (char*)lds + 98304 + (buf) * 32768 + tid * 16;            \
    const char* s_ = bBase + (size_t)(ktx) * 32768;                      \
    g2l16(s_, d_);                  g2l16(s_ + 8192, d_ + 8192);         \
    g2l16(s_ + 16384, d_ + 16384);  g2l16(s_ + 24576, d_ + 24576);       \
  } while (0)

  f32x16 acc[4][2];
#pragma unroll
  for (int i = 0; i < 4; ++i)
#pragma unroll
    for (int j = 0; j < 2; ++j)
#pragma unroll
      for (int r = 0; r < 16; ++r) acc[i][j][r] = 0.f;

  // prologue: A(kt0), B(kt0), A(kt0+1)  -> 12 loads in flight
  STAGE_A(kt0, 0);
  STAGE_B(kt0, 0);
  STAGE_A(kt0 + 1, 1);

  int ab = 0;    // A buf of kt
  int ab2 = 2;   // A buf of kt+2
  int bb = 0;    // B buf of kt

  for (int kt = kt0; kt < ktN; ++kt) {
    // retire A(kt)+B(kt); keep A(kt+1) (4 loads) in flight
    if (kt + 1 < ktN) {
      asm volatile("s_waitcnt vmcnt(4)" ::: "memory");
    } else {
      asm volatile("s_waitcnt vmcnt(0)" ::: "memory");
    }
    __builtin_amdgcn_s_barrier();
    __builtin_amdgcn_sched_barrier(0);

    // stage next tiles (targets were last read at kt-1; safe after barrier)
    if (kt + 1 < ktN) STAGE_B(kt + 1, bb ^ 1);
    if (kt + 2 < ktN) STAGE_A(kt + 2, ab2);

    const char* la = (const char*)lds + ab * 32768;
    const char* lb = (const char*)lds + 98304 + bb * 32768;

#pragma unroll
    for (int ks = 0; ks < 2; ++ks) {
      const int g = ks * 2 + lhalf;       // 8-k group 0..3
      const int aBase = g * 8192 + arow;  // fp32 slots 2g, 2g+1
      f16x8 ah[4], al[4];
#pragma unroll
      for (int mf = 0; mf < 4; ++mf) {
        f32x4 v0 = *(const f32x4*)(la + aBase + mf * 512);
        f32x4 v1 = *(const f32x4*)(la + aBase + 4096 + mf * 512);
        split8(v0, v1, ah[mf], al[mf]);
      }
#pragma unroll
      for (int nf = 0; nf < 2; ++nf) {
        f16x8 bh = *(const f16x8*)(lb + g * 4096 + brow + nf * 512);
        f16x8 bl = *(const f16x8*)(lb + 16384 + g * 4096 + brow + nf * 512);
        __builtin_amdgcn_s_setprio(1);
#pragma unroll
        for (int mf = 0; mf < 4; ++mf) {
          acc[mf][nf] = __builtin_amdgcn_mfma_f32_32x32x16_f16(ah[mf], bh, acc[mf][nf], 0, 0, 0);
          acc[mf][nf] = __builtin_amdgcn_mfma_f32_32x32x16_f16(ah[mf], bl, acc[mf][nf], 0, 0, 0);
          acc[mf][nf] = __builtin_amdgcn_mfma_f32_32x32x16_f16(al[mf], bh, acc[mf][nf], 0, 0, 0);
        }
        __builtin_amdgcn_s_setprio(0);
      }
    }

    ab = (ab == 2) ? 0 : ab + 1;
    ab2 = (ab2 == 2) ? 0 : ab2 + 1;
    bb ^= 1;
  }

  // epilogue: raw partials. 32x32 C/D: col=l&31, row=(r&3)+8*(r>>2)+4*(l>>5)
  float* dst = parts + (size_t)ksp * PART_STRIDE;
  const int row0 = mt * 256 + wm * 128 + (lhalf << 2);
  const int col0 = nt * 256 + wn * 64 + (l & 31);
#pragma unroll
  for (int nf = 0; nf < 2; ++nf)
#pragma unroll
    for (int mf = 0; mf < 4; ++mf)
#pragma unroll
      for (int r = 0; r < 16; ++r) {
        const int row = row0 + mf * 32 + (r & 3) + ((r >> 2) << 3);
        dst[(size_t)row * HID_SZ + col0 + nf * 32] = acc[mf][nf][r];
      }
#undef STAGE_A
#undef STAGE_B
}

// ---- fallback fp32 vector GEMM (used only if ws tiny); writes biased h ----
__global__ __launch_bounds__(256) void gemm_h_kernel(
    const float* __restrict__ x, const float* __restrict__ W1,
    const float* __restrict__ b1, float* __restrict__ h_all) {
  __shared__ float As[16][128];
  __shared__ float Bs[16][128];
  const int tid = threadIdx.x;
  const int tx = tid & 15;
  const int ty = tid >> 4;
  const int m0 = blockIdx.x * 128;
  const int n0 = blockIdx.y * 128;
  const int lrow = tid >> 1;
  const int lcol = (tid & 1) * 8;
  const int gm = m0 + lrow;
  const int bb = gm & (B_SZ - 1);
  const int tt = gm >> 7;
  const float* aptr = x + ((size_t)bb * T_STEPS + tt) * F_SZ + lcol;
  const float* bptr = W1 + (size_t)(n0 + lrow) * F_SZ + lcol;
  float acc[8][8];
#pragma unroll
  for (int i = 0; i < 8; ++i)
#pragma unroll
    for (int j = 0; j < 8; ++j) acc[i][j] = 0.f;
  for (int k0 = 0; k0 < F_SZ; k0 += 16) {
    float4 av0 = *(const float4*)(aptr + k0);
    float4 av1 = *(const float4*)(aptr + k0 + 4);
    float4 bv0 = *(const float4*)(bptr + k0);
    float4 bv1 = *(const float4*)(bptr + k0 + 4);
    As[lcol + 0][lrow] = av0.x; As[lcol + 1][lrow] = av0.y;
    As[lcol + 2][lrow] = av0.z; As[lcol + 3][lrow] = av0.w;
    As[lcol + 4][lrow] = av1.x; As[lcol + 5][lrow] = av1.y;
    As[lcol + 6][lrow] = av1.z; As[lcol + 7][lrow] = av1.w;
    Bs[lcol + 0][lrow] = bv0.x; Bs[lcol + 1][lrow] = bv0.y;
    Bs[lcol + 2][lrow] = bv0.z; Bs[lcol + 3][lrow] = bv0.w;
    Bs[lcol + 4][lrow] = bv1.x; Bs[lcol + 5][lrow] = bv1.y;
    Bs[lcol + 6][lrow] = bv1.z; Bs[lcol + 7][lrow] = bv1.w;
    __syncthreads();
#pragma unroll
    for (int k = 0; k < 16; ++k) {
      float4 a0 = *(const float4*)&As[k][ty * 8];
      float4 a1 = *(const float4*)&As[k][ty * 8 + 4];
      float4 q0 = *(const float4*)&Bs[k][tx * 8];
      float4 q1 = *(const float4*)&Bs[k][tx * 8 + 4];
      float ar[8] = {a0.x, a0.y, a0.z, a0.w, a1.x, a1.y, a1.z, a1.w};
      float br[8] = {q0.x, q0.y, q0.z, q0.w, q1.x, q1.y, q1.z, q1.w};
#pragma unroll
      for (int i = 0; i < 8; ++i)
#pragma unroll
        for (int j = 0; j < 8; ++j)
          acc[i][j] = fmaf(ar[i], br[j], acc[i][j]);
    }
    __syncthreads();
  }
#pragma unroll
  for (int i = 0; i < 8; ++i) {
    const int gm2 = m0 + ty * 8 + i;
    float* orow = h_all + (size_t)gm2 * HID_SZ + n0 + tx * 8;
    const float* brow = b1 + n0 + tx * 8;
#pragma unroll
    for (int j = 0; j < 8; ++j) orow[j] = acc[i][j] + brow[j];
  }
}

// ---- LIF phase 1: hidden-layer dynamics + Wo partial sums ------------------
// mode 1: sum exactly 4 K-split slots; mode 0: parts[0] is prebiased h.
__global__ __launch_bounds__(256) void lif_hidden_kernel(
    const float* __restrict__ parts, const float* __restrict__ b1,
    const float* __restrict__ Wo, float* __restrict__ oc, int mode) {
  const int b = blockIdx.x & 127;
  const int half = blockIdx.x >> 7;
  const int tid = threadIdx.x;
  const int h0 = half * 1024;
  float mem1[4], wo0[4], wo1[4], bv[4];
#pragma unroll
  for (int i = 0; i < 4; ++i) {
    const int hid = h0 + 256 * i + tid;
    mem1[i] = 0.f;
    wo0[i] = Wo[hid];
    wo1[i] = Wo[HID_SZ + hid];
    bv[i] = b1[hid];
  }
  __shared__ float partial[4][2];
  for (int t = 0; t < T_STEPS; ++t) {
    const int row = t * B_SZ + b;
    const size_t rowb = (size_t)row * HID_SZ;
    float pr0 = 0.f, pr1 = 0.f;
#pragma unroll
    for (int i = 0; i < 4; ++i) {
      const int hid = h0 + 256 * i + tid;
      const size_t idx = rowb + hid;
      float h;
      if (mode == 1) {
        float s = (parts[idx] + parts[idx + PART_STRIDE]) +
                  (parts[idx + 2 * PART_STRIDE] + parts[idx + 3 * PART_STRIDE]);
        h = s * 0.0078125f + bv[i];
      } else {
        h = parts[idx];
      }
      float r1 = mem1[i] > 1.0f ? 1.0f : 0.0f;
      float m = 0.9f * mem1[i] + h - r1;
      mem1[i] = m;
      if (m > 1.0f) { pr0 += wo0[i]; pr1 += wo1[i]; }
    }
#pragma unroll
    for (int off = 32; off > 0; off >>= 1) {
      pr0 += __shfl_down(pr0, off);
      pr1 += __shfl_down(pr1, off);
    }
    if ((tid & 63) == 0) { partial[tid >> 6][0] = pr0; partial[tid >> 6][1] = pr1; }
    __syncthreads();
    if (tid == 0) {
      const size_t o = (((size_t)b * 2 + half) * T_STEPS + t) * 2;
      oc[o + 0] = partial[0][0] + partial[1][0] + partial[2][0] + partial[3][0];
      oc[o + 1] = partial[0][1] + partial[1][1] + partial[2][1] + partial[3][1];
    }
    __syncthreads();
  }
}

// ---- LIF phase 2: output-layer membrane scan + spike count -----------------
__global__ __launch_bounds__(128) void lif_out_kernel(
    const float* __restrict__ oc, const float* __restrict__ bo,
    float* __restrict__ out) {
  const int b = threadIdx.x;
  float memo0 = 0.f, memo1 = 0.f, a0 = 0.f, a1 = 0.f;
  const float bo0 = bo[0], bo1 = bo[1];
  for (int t = 0; t < T_STEPS; ++t) {
    const size_t i0 = (((size_t)b * 2 + 0) * T_STEPS + t) * 2;
    const size_t i1 = (((size_t)b * 2 + 1) * T_STEPS + t) * 2;
    float o0 = oc[i0] + oc[i1] + bo0;
    float o1 = oc[i0 + 1] + oc[i1 + 1] + bo1;
    float ro0 = memo0 > 1.0f ? 1.0f : 0.0f;
    float ro1 = memo1 > 1.0f ? 1.0f : 0.0f;
    memo0 = 0.9f * memo0 + o0 - ro0;
    memo1 = 0.9f * memo1 + o1 - ro1;
    a0 += memo0 > 1.0f ? 1.0f : 0.0f;
    a1 += memo1 > 1.0f ? 1.0f : 0.0f;
  }
  out[b * 2 + 0] = a0;
  out[b * 2 + 1] = a1;
}

extern "C" void kernel_launch(void* const* d_in, const int* in_sizes, int n_in,
                              void* d_out, int out_size, void* d_ws, size_t ws_size,
                              hipStream_t stream) {
  const float* x  = (const float*)d_in[0];
  const float* W1 = (const float*)d_in[1];
  const float* b1 = (const float*)d_in[2];
  const float* Wo = (const float*)d_in[3];
  const float* bo = (const float*)d_in[4];
  float* out = (float*)d_out;

  const size_t part_bytes = PART_STRIDE * 4;                 // 27.26 MB
  const size_t b2_bytes = (size_t)8 * KT * 32768;            // 100.66 MB
  const size_t oc_bytes = (size_t)128 * 2 * T_STEPS * 2 * 4; // 51.2 KB
  char* ws = (char*)d_ws;
  float* parts = (float*)ws;

  if (ws_size >= 4 * part_bytes + b2_bytes + oc_bytes) {
    char* B2 = ws + 4 * part_bytes;
    float* oc = (float*)(B2 + b2_bytes);
    conv_w_kernel<<<2048, 256, 0, stream>>>(W1, B2);
    gemm_tile_kernel<<<416, 512, 0, stream>>>(x, B2, parts);
    lif_hidden_kernel<<<256, 256, 0, stream>>>(parts, b1, Wo, oc, 1);
    lif_out_kernel<<<1, 128, 0, stream>>>(oc, bo, out);
  } else {
    float* oc = (float*)(ws + part_bytes);
    dim3 grid(25, 16);
    gemm_h_kernel<<<grid, 256, 0, stream>>>(x, W1, b1, (float*)ws);
    lif_hidden_kernel<<<256, 256, 0, stream>>>((const float*)ws, b1, Wo, oc, 0);
    lif_out_kernel<<<1, 128, 0, stream>>>(oc, bo, out);
  }
}

// Round 9
// 628.092 us; speedup vs baseline: 1.0768x; 1.0768x over previous
//
#include <hip/hip_runtime.h>

// SNN classifier: h = x @ W1^T + b1 via f16 split-2 MFMA (3 terms), LIF scan.
//   x [128,25,12288] f32 ; W1 [2048,12288] ; Wo [2,2048]
// a = ah+al, w*128 = bh+bl (both PRE-converted to f16 hi/lo LDS images);
// h*128 = ah*bh + ah*bl + al*bh  (fp32-grade, absmax 0 since r2).
//
// GEMM: 128x128 tile, 256 thr (4 waves 2Mx2N), wave-tile 64x64 of 32x32x16.
// LDS 64KB = 2 x (A 16K | B 16K) -> TWO blocks/CU (8 waves/CU, independent
// phases: one block's MFMA hides the other's stage/drain — m114 overlap;
// fixes r8's 1-block lockstep at MfmaUtil 34%). Grid 1664 = 26 mt x 16 nt x
// 4 ksp, mt slowest (r8-proven sliding window: FETCH 260MB, L3-resident).
// LDS images [slot 0..7][row 0..127][16B]: slot = 8-k group (hi 0-3, lo
// 4-7); half-wave-contiguous ds_read_b128, conflict-free (r4/r7/r8: 0).
// Per kt per block: 8 g2l16 stages, 32 ds_read_b128, 96 MFMA.
// Partials to slot=ksp of 4 buffers; LIF phase 1 (256 blocks) sums 4 slots
// + Wo partials; phase 2 (1 block) scans the 2-wide output layer.

#define T_STEPS 25
#define B_SZ    128
#define F_SZ    12288
#define HID_SZ  2048
#define KT      384
#define M_PAD   3328           // 26 * 128
#define PART_STRIDE ((size_t)M_PAD * HID_SZ)

typedef __attribute__((ext_vector_type(8))) _Float16 f16x8;
typedef __attribute__((ext_vector_type(4))) float f32x4;
typedef __attribute__((ext_vector_type(16))) float f32x16;

__device__ __forceinline__ void g2l16(const void* g, void* l) {
  __builtin_amdgcn_global_load_lds(
      (const __attribute__((address_space(1))) void*)g,
      (__attribute__((address_space(3))) void*)l, 16, 0, 0);
}

// ---- conv_x: x -> A2 [mt*KT+kt](16KB: [slot][row 0..127][16B]) -------------
__global__ __launch_bounds__(256) void conv_x_kernel(
    const float* __restrict__ x, char* __restrict__ A2) {
  const int total = 26 * KT * 128 * 4;   // (mtkt, r, s)
  for (int i = blockIdx.x * 256 + threadIdx.x; i < total; i += gridDim.x * 256) {
    const int s = i & 3;
    const int r = (i >> 2) & 127;
    const int mtkt = i >> 9;             // mt*KT + kt
    const int kt = mtkt % KT;
    const int m = (mtkt / KT) * 128 + r;
    const int b = m & 127;
    const int t = m >> 7;
    f16x8 hi = {0, 0, 0, 0, 0, 0, 0, 0};
    f16x8 lo = {0, 0, 0, 0, 0, 0, 0, 0};
    if (t < T_STEPS) {
      const float* src = x + ((size_t)(b * T_STEPS + t)) * F_SZ + kt * 32 + s * 8;
      float4 v0 = *(const float4*)src;
      float4 v1 = *(const float4*)(src + 4);
      float vf[8] = {v0.x, v0.y, v0.z, v0.w, v1.x, v1.y, v1.z, v1.w};
#pragma unroll
      for (int j = 0; j < 8; ++j) {
        _Float16 h = (_Float16)vf[j];
        hi[j] = h;
        lo[j] = (_Float16)(vf[j] - (float)h);
      }
    }
    char* chunk = A2 + (size_t)mtkt * 16384;
    *(f16x8*)(chunk + s * 2048 + r * 16) = hi;          // slots 0-3: hi
    *(f16x8*)(chunk + (s + 4) * 2048 + r * 16) = lo;    // slots 4-7: lo
  }
}

// ---- conv_w: W1*128 -> B2 [nt*KT+kt](16KB image, 128 cols) -----------------
__global__ __launch_bounds__(256) void conv_w_kernel(
    const float* __restrict__ W1, char* __restrict__ B2) {
  const int total = 16 * KT * 128 * 4;
  for (int i = blockIdx.x * 256 + threadIdx.x; i < total; i += gridDim.x * 256) {
    const int s = i & 3;
    const int c = (i >> 2) & 127;
    const int ntkt = i >> 9;             // nt*KT + kt
    const int kt = ntkt % KT;
    const int n = (ntkt / KT) * 128 + c;
    const float* src = W1 + (size_t)n * F_SZ + kt * 32 + s * 8;
    float4 v0 = *(const float4*)src;
    float4 v1 = *(const float4*)(src + 4);
    float vf[8] = {v0.x, v0.y, v0.z, v0.w, v1.x, v1.y, v1.z, v1.w};
    f16x8 hi, lo;
#pragma unroll
    for (int j = 0; j < 8; ++j) {
      float vs = vf[j] * 128.0f;         // scale keeps residual f16-normal
      _Float16 h = (_Float16)vs;
      hi[j] = h;
      lo[j] = (_Float16)(vs - (float)h);
    }
    char* chunk = B2 + (size_t)ntkt * 16384;
    *(f16x8*)(chunk + s * 2048 + c * 16) = hi;
    *(f16x8*)(chunk + (s + 4) * 2048 + c * 16) = lo;
  }
}

// ---- tiled MFMA GEMM: 1664 blocks, 128x128 tile, 2 blocks/CU ---------------
__global__ __launch_bounds__(256, 2) void gemm_tile_kernel(
    const char* __restrict__ A2, const char* __restrict__ B2,
    float* __restrict__ parts) {
  __shared__ __align__(16) char lds[65536];   // 2 x (A 16K | B 16K)
  const int tid = threadIdx.x;
  const int l = tid & 63;
  const int w = tid >> 6;      // wave 0..3
  const int wm = w >> 1;       // 0..1: rows wm*64
  const int wn = w & 1;        // 0..1: cols wn*64
  const int lhalf = l >> 5;

  const int bid = blockIdx.x;          // mt slowest: sliding-window locality
  const int mt = bid >> 6;             // 0..25
  const int nt = (bid >> 2) & 15;      // 0..15
  const int ksp = bid & 3;             // 0..3
  const int kt0 = ksp * 96;
  const int ktN = kt0 + 96;

  const char* aC = A2 + (size_t)mt * KT * 16384;
  const char* bC = B2 + (size_t)nt * KT * 16384;
  const int arow = (wm * 64 + (l & 31)) * 16;
  const int brow = (wn * 64 + (l & 31)) * 16;

#define STAGE(ktx, buf)                                                  \
  do {                                                                   \
    char* d_ = (char*)lds + (buf) * 32768 + tid * 16;                    \
    const char* a_ = aC + (size_t)(ktx) * 16384 + tid * 16;              \
    const char* b_ = bC + (size_t)(ktx) * 16384 + tid * 16;              \
    g2l16(a_, d_);          g2l16(a_ + 4096, d_ + 4096);                 \
    g2l16(a_ + 8192, d_ + 8192);  g2l16(a_ + 12288, d_ + 12288);         \
    g2l16(b_, d_ + 16384);  g2l16(b_ + 4096, d_ + 20480);                \
    g2l16(b_ + 8192, d_ + 24576); g2l16(b_ + 12288, d_ + 28672);         \
  } while (0)

  f32x16 acc[2][2];
#pragma unroll
  for (int i = 0; i < 2; ++i)
#pragma unroll
    for (int j = 0; j < 2; ++j)
#pragma unroll
      for (int r = 0; r < 16; ++r) acc[i][j][r] = 0.f;

  STAGE(kt0, 0);   // prologue
  int buf = 0;

  for (int kt = kt0; kt < ktN; ++kt) {
    __syncthreads();             // drains stage(kt); other block hides stall
    if (kt + 1 < ktN) STAGE(kt + 1, buf ^ 1);

    const char* la = (const char*)lds + buf * 32768;
    const char* lb = la + 16384;

#pragma unroll
    for (int ks = 0; ks < 2; ++ks) {
      const int g = ks * 2 + lhalf;        // 8-k group 0..3
      f16x8 ah[2], al[2], bh[2], bl[2];
#pragma unroll
      for (int mf = 0; mf < 2; ++mf) {
        ah[mf] = *(const f16x8*)(la + g * 2048 + arow + mf * 512);
        al[mf] = *(const f16x8*)(la + (g + 4) * 2048 + arow + mf * 512);
      }
#pragma unroll
      for (int nf = 0; nf < 2; ++nf) {
        bh[nf] = *(const f16x8*)(lb + g * 2048 + brow + nf * 512);
        bl[nf] = *(const f16x8*)(lb + (g + 4) * 2048 + brow + nf * 512);
      }
      __builtin_amdgcn_s_setprio(1);
#pragma unroll
      for (int mf = 0; mf < 2; ++mf)
#pragma unroll
        for (int nf = 0; nf < 2; ++nf) {
          acc[mf][nf] = __builtin_amdgcn_mfma_f32_32x32x16_f16(ah[mf], bh[nf], acc[mf][nf], 0, 0, 0);
          acc[mf][nf] = __builtin_amdgcn_mfma_f32_32x32x16_f16(ah[mf], bl[nf], acc[mf][nf], 0, 0, 0);
          acc[mf][nf] = __builtin_amdgcn_mfma_f32_32x32x16_f16(al[mf], bh[nf], acc[mf][nf], 0, 0, 0);
        }
      __builtin_amdgcn_s_setprio(0);
    }
    buf ^= 1;
  }

  // epilogue: raw partials. 32x32 C/D: col=l&31, row=(r&3)+8*(r>>2)+4*(l>>5)
  float* dst = parts + (size_t)ksp * PART_STRIDE;
  const int row0 = mt * 128 + wm * 64 + (lhalf << 2);
  const int col0 = nt * 128 + wn * 64 + (l & 31);
#pragma unroll
  for (int nf = 0; nf < 2; ++nf)
#pragma unroll
    for (int mf = 0; mf < 2; ++mf)
#pragma unroll
      for (int r = 0; r < 16; ++r) {
        const int row = row0 + mf * 32 + (r & 3) + ((r >> 2) << 3);
        dst[(size_t)row * HID_SZ + col0 + nf * 32] = acc[mf][nf][r];
      }
#undef STAGE
}

// ---- fallback fp32 vector GEMM (used only if ws tiny); writes biased h ----
__global__ __launch_bounds__(256) void gemm_h_kernel(
    const float* __restrict__ x, const float* __restrict__ W1,
    const float* __restrict__ b1, float* __restrict__ h_all) {
  __shared__ float As[16][128];
  __shared__ float Bs[16][128];
  const int tid = threadIdx.x;
  const int tx = tid & 15;
  const int ty = tid >> 4;
  const int m0 = blockIdx.x * 128;
  const int n0 = blockIdx.y * 128;
  const int lrow = tid >> 1;
  const int lcol = (tid & 1) * 8;
  const int gm = m0 + lrow;
  const int bb = gm & (B_SZ - 1);
  const int tt = gm >> 7;
  const float* aptr = x + ((size_t)bb * T_STEPS + tt) * F_SZ + lcol;
  const float* bptr = W1 + (size_t)(n0 + lrow) * F_SZ + lcol;
  float acc[8][8];
#pragma unroll
  for (int i = 0; i < 8; ++i)
#pragma unroll
    for (int j = 0; j < 8; ++j) acc[i][j] = 0.f;
  for (int k0 = 0; k0 < F_SZ; k0 += 16) {
    float4 av0 = *(const float4*)(aptr + k0);
    float4 av1 = *(const float4*)(aptr + k0 + 4);
    float4 bv0 = *(const float4*)(bptr + k0);
    float4 bv1 = *(const float4*)(bptr + k0 + 4);
    As[lcol + 0][lrow] = av0.x; As[lcol + 1][lrow] = av0.y;
    As[lcol + 2][lrow] = av0.z; As[lcol + 3][lrow] = av0.w;
    As[lcol + 4][lrow] = av1.x; As[lcol + 5][lrow] = av1.y;
    As[lcol + 6][lrow] = av1.z; As[lcol + 7][lrow] = av1.w;
    Bs[lcol + 0][lrow] = bv0.x; Bs[lcol + 1][lrow] = bv0.y;
    Bs[lcol + 2][lrow] = bv0.z; Bs[lcol + 3][lrow] = bv0.w;
    Bs[lcol + 4][lrow] = bv1.x; Bs[lcol + 5][lrow] = bv1.y;
    Bs[lcol + 6][lrow] = bv1.z; Bs[lcol + 7][lrow] = bv1.w;
    __syncthreads();
#pragma unroll
    for (int k = 0; k < 16; ++k) {
      float4 a0 = *(const float4*)&As[k][ty * 8];
      float4 a1 = *(const float4*)&As[k][ty * 8 + 4];
      float4 q0 = *(const float4*)&Bs[k][tx * 8];
      float4 q1 = *(const float4*)&Bs[k][tx * 8 + 4];
      float ar[8] = {a0.x, a0.y, a0.z, a0.w, a1.x, a1.y, a1.z, a1.w};
      float br[8] = {q0.x, q0.y, q0.z, q0.w, q1.x, q1.y, q1.z, q1.w};
#pragma unroll
      for (int i = 0; i < 8; ++i)
#pragma unroll
        for (int j = 0; j < 8; ++j)
          acc[i][j] = fmaf(ar[i], br[j], acc[i][j]);
    }
    __syncthreads();
  }
#pragma unroll
  for (int i = 0; i < 8; ++i) {
    const int gm2 = m0 + ty * 8 + i;
    float* orow = h_all + (size_t)gm2 * HID_SZ + n0 + tx * 8;
    const float* brow = b1 + n0 + tx * 8;
#pragma unroll
    for (int j = 0; j < 8; ++j) orow[j] = acc[i][j] + brow[j];
  }
}

// ---- LIF phase 1: hidden-layer dynamics + Wo partial sums ------------------
// mode 1: sum exactly 4 K-split slots; mode 0: parts[0] is prebiased h.
__global__ __launch_bounds__(256) void lif_hidden_kernel(
    const float* __restrict__ parts, const float* __restrict__ b1,
    const float* __restrict__ Wo, float* __restrict__ oc, int mode) {
  const int b = blockIdx.x & 127;
  const int half = blockIdx.x >> 7;
  const int tid = threadIdx.x;
  const int h0 = half * 1024;
  float mem1[4], wo0[4], wo1[4], bv[4];
#pragma unroll
  for (int i = 0; i < 4; ++i) {
    const int hid = h0 + 256 * i + tid;
    mem1[i] = 0.f;
    wo0[i] = Wo[hid];
    wo1[i] = Wo[HID_SZ + hid];
    bv[i] = b1[hid];
  }
  __shared__ float partial[4][2];
  for (int t = 0; t < T_STEPS; ++t) {
    const int row = t * B_SZ + b;
    const size_t rowb = (size_t)row * HID_SZ;
    float pr0 = 0.f, pr1 = 0.f;
#pragma unroll
    for (int i = 0; i < 4; ++i) {
      const int hid = h0 + 256 * i + tid;
      const size_t idx = rowb + hid;
      float h;
      if (mode == 1) {
        float s = (parts[idx] + parts[idx + PART_STRIDE]) +
                  (parts[idx + 2 * PART_STRIDE] + parts[idx + 3 * PART_STRIDE]);
        h = s * 0.0078125f + bv[i];
      } else {
        h = parts[idx];
      }
      float r1 = mem1[i] > 1.0f ? 1.0f : 0.0f;
      float m = 0.9f * mem1[i] + h - r1;
      mem1[i] = m;
      if (m > 1.0f) { pr0 += wo0[i]; pr1 += wo1[i]; }
    }
#pragma unroll
    for (int off = 32; off > 0; off >>= 1) {
      pr0 += __shfl_down(pr0, off);
      pr1 += __shfl_down(pr1, off);
    }
    if ((tid & 63) == 0) { partial[tid >> 6][0] = pr0; partial[tid >> 6][1] = pr1; }
    __syncthreads();
    if (tid == 0) {
      const size_t o = (((size_t)b * 2 + half) * T_STEPS + t) * 2;
      oc[o + 0] = partial[0][0] + partial[1][0] + partial[2][0] + partial[3][0];
      oc[o + 1] = partial[0][1] + partial[1][1] + partial[2][1] + partial[3][1];
    }
    __syncthreads();
  }
}

// ---- LIF phase 2: output-layer membrane scan + spike count -----------------
__global__ __launch_bounds__(128) void lif_out_kernel(
    const float* __restrict__ oc, const float* __restrict__ bo,
    float* __restrict__ out) {
  const int b = threadIdx.x;
  float memo0 = 0.f, memo1 = 0.f, a0 = 0.f, a1 = 0.f;
  const float bo0 = bo[0], bo1 = bo[1];
  for (int t = 0; t < T_STEPS; ++t) {
    const size_t i0 = (((size_t)b * 2 + 0) * T_STEPS + t) * 2;
    const size_t i1 = (((size_t)b * 2 + 1) * T_STEPS + t) * 2;
    float o0 = oc[i0] + oc[i1] + bo0;
    float o1 = oc[i0 + 1] + oc[i1 + 1] + bo1;
    float ro0 = memo0 > 1.0f ? 1.0f : 0.0f;
    float ro1 = memo1 > 1.0f ? 1.0f : 0.0f;
    memo0 = 0.9f * memo0 + o0 - ro0;
    memo1 = 0.9f * memo1 + o1 - ro1;
    a0 += memo0 > 1.0f ? 1.0f : 0.0f;
    a1 += memo1 > 1.0f ? 1.0f : 0.0f;
  }
  out[b * 2 + 0] = a0;
  out[b * 2 + 1] = a1;
}

extern "C" void kernel_launch(void* const* d_in, const int* in_sizes, int n_in,
                              void* d_out, int out_size, void* d_ws, size_t ws_size,
                              hipStream_t stream) {
  const float* x  = (const float*)d_in[0];
  const float* W1 = (const float*)d_in[1];
  const float* b1 = (const float*)d_in[2];
  const float* Wo = (const float*)d_in[3];
  const float* bo = (const float*)d_in[4];
  float* out = (float*)d_out;

  const size_t part_bytes = PART_STRIDE * 4;                 // 27.26 MB
  const size_t a2_bytes = (size_t)26 * KT * 16384;           // 163.6 MB
  const size_t b2_bytes = (size_t)16 * KT * 16384;           // 100.7 MB
  const size_t oc_bytes = (size_t)128 * 2 * T_STEPS * 2 * 4; // 51.2 KB
  char* ws = (char*)d_ws;
  float* parts = (float*)ws;

  if (ws_size >= 4 * part_bytes + a2_bytes + b2_bytes + oc_bytes) {
    char* A2 = ws + 4 * part_bytes;
    char* B2 = A2 + a2_bytes;
    float* oc = (float*)(B2 + b2_bytes);
    conv_x_kernel<<<2048, 256, 0, stream>>>(x, A2);
    conv_w_kernel<<<2048, 256, 0, stream>>>(W1, B2);
    gemm_tile_kernel<<<1664, 256, 0, stream>>>(A2, B2, parts);
    lif_hidden_kernel<<<256, 256, 0, stream>>>(parts, b1, Wo, oc, 1);
    lif_out_kernel<<<1, 128, 0, stream>>>(oc, bo, out);
  } else {
    float* oc = (float*)(ws + part_bytes);
    dim3 grid(25, 16);
    gemm_h_kernel<<<grid, 256, 0, stream>>>(x, W1, b1, (float*)ws);
    lif_hidden_kernel<<<256, 256, 0, stream>>>((const float*)ws, b1, Wo, oc, 0);
    lif_out_kernel<<<1, 128, 0, stream>>>(oc, bo, out);
  }
}

// Round 10
// 567.377 us; speedup vs baseline: 1.1920x; 1.1070x over previous
//
#include <hip/hip_runtime.h>

// SNN classifier: h = x @ W1^T + b1 via f16 split-2 MFMA (3 terms), LIF scan.
//   x [128,25,12288] f32 ; W1 [2048,12288] ; Wo [2,2048]
// a = ah+al, w*128 = bh+bl (PRE-converted f16 hi/lo images);
// h*128 = ah*bh + ah*bl + al*bh  (fp32-grade, absmax 0 r2-r9).
//
// GEMM: r4 geometry + 32x32x16 frags (r9-proven maps): 256x256 tile, 512
// thr (8 waves 2Mx4N), wave-tile 128x64, K-split 2 -> 208 blocks (=8x26
// bijective XCD swizzle). LDS 128KB = 2 x (A 32K | B 32K) double buffer;
// one __syncthreads per kt; STAGE(kt+1) issued right after the barrier so
// its 16 loads are a full ~4400-cyc tile old at the next drain (no stall).
// Per kt per wave: 2 ks-clusters of {12 ds_read_b128 -> 24 MFMA}; full
// unroll lets the compiler hoist ks=1 reads under ks=0 MFMAs (fine-grained
// lgkmcnt). setprio(1) around MFMA clusters only.
// Images [slot 0..7][row 0..255][16B]: slot = 8-k group (hi 0-3, lo 4-7);
// 32-lane-contiguous ds_read_b128 -> conflict-free (r4/r7/r8/r9: 0).
// Partials: slot=sp of 2 buffers; LIF phase 1 (256 blocks) sums 2 slots +
// Wo partials; phase 2 (1 block) scans the 2-wide output layer.

#define T_STEPS 25
#define B_SZ    128
#define F_SZ    12288
#define HID_SZ  2048
#define KT      384
#define M_PAD   3328           // 13 * 256
#define PART_STRIDE ((size_t)M_PAD * HID_SZ)

typedef __attribute__((ext_vector_type(8))) _Float16 f16x8;
typedef __attribute__((ext_vector_type(4))) float f32x4;
typedef __attribute__((ext_vector_type(16))) float f32x16;

__device__ __forceinline__ void g2l16(const void* g, void* l) {
  __builtin_amdgcn_global_load_lds(
      (const __attribute__((address_space(1))) void*)g,
      (__attribute__((address_space(3))) void*)l, 16, 0, 0);
}

// ---- conv_x: x -> A2 [mt*KT+kt](32KB: [slot 0..7][row 0..255][16B]) --------
__global__ __launch_bounds__(256) void conv_x_kernel(
    const float* __restrict__ x, char* __restrict__ A2) {
  const int total = 13 * KT * 256 * 4;   // (mtkt, r, s)
  for (int i = blockIdx.x * 256 + threadIdx.x; i < total; i += gridDim.x * 256) {
    const int s = i & 3;
    const int r = (i >> 2) & 255;
    const int mtkt = i >> 10;            // mt*KT + kt
    const int kt = mtkt % KT;
    const int m = (mtkt / KT) * 256 + r;
    const int b = m & 127;
    const int t = m >> 7;
    f16x8 hi = {0, 0, 0, 0, 0, 0, 0, 0};
    f16x8 lo = {0, 0, 0, 0, 0, 0, 0, 0};
    if (t < T_STEPS) {
      const float* src = x + ((size_t)(b * T_STEPS + t)) * F_SZ + kt * 32 + s * 8;
      float4 v0 = *(const float4*)src;
      float4 v1 = *(const float4*)(src + 4);
      float vf[8] = {v0.x, v0.y, v0.z, v0.w, v1.x, v1.y, v1.z, v1.w};
#pragma unroll
      for (int j = 0; j < 8; ++j) {
        _Float16 h = (_Float16)vf[j];
        hi[j] = h;
        lo[j] = (_Float16)(vf[j] - (float)h);
      }
    }
    char* chunk = A2 + (size_t)mtkt * 32768;
    *(f16x8*)(chunk + s * 4096 + r * 16) = hi;          // slots 0-3: hi
    *(f16x8*)(chunk + (s + 4) * 4096 + r * 16) = lo;    // slots 4-7: lo
  }
}

// ---- conv_w: W1*128 -> B2 [nt*KT+kt](32KB: [slot][col 0..255][16B]) --------
__global__ __launch_bounds__(256) void conv_w_kernel(
    const float* __restrict__ W1, char* __restrict__ B2) {
  const int total = 8 * KT * 256 * 4;
  for (int i = blockIdx.x * 256 + threadIdx.x; i < total; i += gridDim.x * 256) {
    const int s = i & 3;
    const int c = (i >> 2) & 255;
    const int ntkt = i >> 10;            // nt*KT + kt
    const int kt = ntkt % KT;
    const int n = (ntkt / KT) * 256 + c;
    const float* src = W1 + (size_t)n * F_SZ + kt * 32 + s * 8;
    float4 v0 = *(const float4*)src;
    float4 v1 = *(const float4*)(src + 4);
    float vf[8] = {v0.x, v0.y, v0.z, v0.w, v1.x, v1.y, v1.z, v1.w};
    f16x8 hi, lo;
#pragma unroll
    for (int j = 0; j < 8; ++j) {
      float vs = vf[j] * 128.0f;         // scale keeps residual f16-normal
      _Float16 h = (_Float16)vs;
      hi[j] = h;
      lo[j] = (_Float16)(vs - (float)h);
    }
    char* chunk = B2 + (size_t)ntkt * 32768;
    *(f16x8*)(chunk + s * 4096 + c * 16) = hi;
    *(f16x8*)(chunk + (s + 4) * 4096 + c * 16) = lo;
  }
}

// ---- tiled MFMA GEMM: 208 blocks, 256x256 tile, K-split 2 ------------------
__global__ __launch_bounds__(512, 1) void gemm_tile_kernel(
    const char* __restrict__ A2, const char* __restrict__ B2,
    float* __restrict__ parts) {
  __shared__ __align__(16) char lds[131072];  // 2 x (A 32K | B 32K)
  const int tid = threadIdx.x;
  const int l = tid & 63;
  const int w = tid >> 6;      // wave 0..7
  const int wm = w >> 2;       // 0..1: rows wm*128
  const int wn = w & 3;        // 0..3: cols wn*64
  const int lhalf = l >> 5;

  // XCD-aware bijective swizzle (208 = 8 XCDs x 26); within an XCD,
  // consecutive swz share mt (A-chunk L2 reuse across nt).
  const int swz = (blockIdx.x & 7) * 26 + (blockIdx.x >> 3);
  const int sp = swz & 1;              // K-split half
  const int mnt = swz >> 1;            // 0..103
  const int mt = mnt >> 3;             // 0..12
  const int nt = mnt & 7;              // 0..7
  const int kt0 = sp * 192;
  const int ktN = kt0 + 192;

  const char* aC = A2 + (size_t)mt * KT * 32768;
  const char* bC = B2 + (size_t)nt * KT * 32768;
  const int arow = (wm * 128 + (l & 31)) * 16;
  const int brow = (wn * 64 + (l & 31)) * 16;

#define STAGE(ktx, buf)                                                  \
  do {                                                                   \
    char* d_ = (char*)lds + (buf) * 65536 + tid * 16;                    \
    const char* a_ = aC + (size_t)(ktx) * 32768 + tid * 16;              \
    const char* b_ = bC + (size_t)(ktx) * 32768 + tid * 16;              \
    g2l16(a_, d_);                 g2l16(a_ + 8192, d_ + 8192);          \
    g2l16(a_ + 16384, d_ + 16384); g2l16(a_ + 24576, d_ + 24576);        \
    g2l16(b_, d_ + 32768);         g2l16(b_ + 8192, d_ + 40960);         \
    g2l16(b_ + 16384, d_ + 49152); g2l16(b_ + 24576, d_ + 57344);        \
  } while (0)

  f32x16 acc[4][2];
#pragma unroll
  for (int i = 0; i < 4; ++i)
#pragma unroll
    for (int j = 0; j < 2; ++j)
#pragma unroll
      for (int r = 0; r < 16; ++r) acc[i][j][r] = 0.f;

  STAGE(kt0, 0);   // prologue
  int buf = 0;

  for (int kt = kt0; kt < ktN; ++kt) {
    __syncthreads();             // drains stage(kt), issued a full tile ago
    if (kt + 1 < ktN) STAGE(kt + 1, buf ^ 1);

    const char* la = (const char*)lds + buf * 65536;
    const char* lb = la + 32768;

#pragma unroll
    for (int ks = 0; ks < 2; ++ks) {
      const int g = ks * 2 + lhalf;        // 8-k group 0..3
      f16x8 ah[4], al[4], bh[2], bl[2];
#pragma unroll
      for (int mf = 0; mf < 4; ++mf) {
        ah[mf] = *(const f16x8*)(la + g * 4096 + arow + mf * 512);
        al[mf] = *(const f16x8*)(la + (g + 4) * 4096 + arow + mf * 512);
      }
#pragma unroll
      for (int nf = 0; nf < 2; ++nf) {
        bh[nf] = *(const f16x8*)(lb + g * 4096 + brow + nf * 512);
        bl[nf] = *(const f16x8*)(lb + (g + 4) * 4096 + brow + nf * 512);
      }
      __builtin_amdgcn_s_setprio(1);
#pragma unroll
      for (int mf = 0; mf < 4; ++mf)
#pragma unroll
        for (int nf = 0; nf < 2; ++nf) {
          acc[mf][nf] = __builtin_amdgcn_mfma_f32_32x32x16_f16(ah[mf], bh[nf], acc[mf][nf], 0, 0, 0);
          acc[mf][nf] = __builtin_amdgcn_mfma_f32_32x32x16_f16(ah[mf], bl[nf], acc[mf][nf], 0, 0, 0);
          acc[mf][nf] = __builtin_amdgcn_mfma_f32_32x32x16_f16(al[mf], bh[nf], acc[mf][nf], 0, 0, 0);
        }
      __builtin_amdgcn_s_setprio(0);
    }
    buf ^= 1;
  }

  // epilogue: raw partials. 32x32 C/D: col=l&31, row=(r&3)+8*(r>>2)+4*(l>>5)
  float* dst = parts + (size_t)sp * PART_STRIDE;
  const int row0 = mt * 256 + wm * 128 + (lhalf << 2);
  const int col0 = nt * 256 + wn * 64 + (l & 31);
#pragma unroll
  for (int nf = 0; nf < 2; ++nf)
#pragma unroll
    for (int mf = 0; mf < 4; ++mf)
#pragma unroll
      for (int r = 0; r < 16; ++r) {
        const int row = row0 + mf * 32 + (r & 3) + ((r >> 2) << 3);
        dst[(size_t)row * HID_SZ + col0 + nf * 32] = acc[mf][nf][r];
      }
#undef STAGE
}

// ---- fallback fp32 vector GEMM (used only if ws tiny); writes biased h ----
__global__ __launch_bounds__(256) void gemm_h_kernel(
    const float* __restrict__ x, const float* __restrict__ W1,
    const float* __restrict__ b1, float* __restrict__ h_all) {
  __shared__ float As[16][128];
  __shared__ float Bs[16][128];
  const int tid = threadIdx.x;
  const int tx = tid & 15;
  const int ty = tid >> 4;
  const int m0 = blockIdx.x * 128;
  const int n0 = blockIdx.y * 128;
  const int lrow = tid >> 1;
  const int lcol = (tid & 1) * 8;
  const int gm = m0 + lrow;
  const int bb = gm & (B_SZ - 1);
  const int tt = gm >> 7;
  const float* aptr = x + ((size_t)bb * T_STEPS + tt) * F_SZ + lcol;
  const float* bptr = W1 + (size_t)(n0 + lrow) * F_SZ + lcol;
  float acc[8][8];
#pragma unroll
  for (int i = 0; i < 8; ++i)
#pragma unroll
    for (int j = 0; j < 8; ++j) acc[i][j] = 0.f;
  for (int k0 = 0; k0 < F_SZ; k0 += 16) {
    float4 av0 = *(const float4*)(aptr + k0);
    float4 av1 = *(const float4*)(aptr + k0 + 4);
    float4 bv0 = *(const float4*)(bptr + k0);
    float4 bv1 = *(const float4*)(bptr + k0 + 4);
    As[lcol + 0][lrow] = av0.x; As[lcol + 1][lrow] = av0.y;
    As[lcol + 2][lrow] = av0.z; As[lcol + 3][lrow] = av0.w;
    As[lcol + 4][lrow] = av1.x; As[lcol + 5][lrow] = av1.y;
    As[lcol + 6][lrow] = av1.z; As[lcol + 7][lrow] = av1.w;
    Bs[lcol + 0][lrow] = bv0.x; Bs[lcol + 1][lrow] = bv0.y;
    Bs[lcol + 2][lrow] = bv0.z; Bs[lcol + 3][lrow] = bv0.w;
    Bs[lcol + 4][lrow] = bv1.x; Bs[lcol + 5][lrow] = bv1.y;
    Bs[lcol + 6][lrow] = bv1.z; Bs[lcol + 7][lrow] = bv1.w;
    __syncthreads();
#pragma unroll
    for (int k = 0; k < 16; ++k) {
      float4 a0 = *(const float4*)&As[k][ty * 8];
      float4 a1 = *(const float4*)&As[k][ty * 8 + 4];
      float4 q0 = *(const float4*)&Bs[k][tx * 8];
      float4 q1 = *(const float4*)&Bs[k][tx * 8 + 4];
      float ar[8] = {a0.x, a0.y, a0.z, a0.w, a1.x, a1.y, a1.z, a1.w};
      float br[8] = {q0.x, q0.y, q0.z, q0.w, q1.x, q1.y, q1.z, q1.w};
#pragma unroll
      for (int i = 0; i < 8; ++i)
#pragma unroll
        for (int j = 0; j < 8; ++j)
          acc[i][j] = fmaf(ar[i], br[j], acc[i][j]);
    }
    __syncthreads();
  }
#pragma unroll
  for (int i = 0; i < 8; ++i) {
    const int gm2 = m0 + ty * 8 + i;
    float* orow = h_all + (size_t)gm2 * HID_SZ + n0 + tx * 8;
    const float* brow = b1 + n0 + tx * 8;
#pragma unroll
    for (int j = 0; j < 8; ++j) orow[j] = acc[i][j] + brow[j];
  }
}

// ---- LIF phase 1: hidden-layer dynamics + Wo partial sums ------------------
// mode 1: sum exactly 2 K-split slots; mode 0: parts[0] is prebiased h.
__global__ __launch_bounds__(256) void lif_hidden_kernel(
    const float* __restrict__ parts, const float* __restrict__ b1,
    const float* __restrict__ Wo, float* __restrict__ oc, int mode) {
  const int b = blockIdx.x & 127;
  const int half = blockIdx.x >> 7;
  const int tid = threadIdx.x;
  const int h0 = half * 1024;
  float mem1[4], wo0[4], wo1[4], bv[4];
#pragma unroll
  for (int i = 0; i < 4; ++i) {
    const int hid = h0 + 256 * i + tid;
    mem1[i] = 0.f;
    wo0[i] = Wo[hid];
    wo1[i] = Wo[HID_SZ + hid];
    bv[i] = b1[hid];
  }
  __shared__ float partial[4][2];
  for (int t = 0; t < T_STEPS; ++t) {
    const int row = t * B_SZ + b;
    const size_t rowb = (size_t)row * HID_SZ;
    float pr0 = 0.f, pr1 = 0.f;
#pragma unroll
    for (int i = 0; i < 4; ++i) {
      const int hid = h0 + 256 * i + tid;
      const size_t idx = rowb + hid;
      float h;
      if (mode == 1) {
        float s = parts[idx] + parts[idx + PART_STRIDE];
        h = s * 0.0078125f + bv[i];
      } else {
        h = parts[idx];
      }
      float r1 = mem1[i] > 1.0f ? 1.0f : 0.0f;
      float m = 0.9f * mem1[i] + h - r1;
      mem1[i] = m;
      if (m > 1.0f) { pr0 += wo0[i]; pr1 += wo1[i]; }
    }
#pragma unroll
    for (int off = 32; off > 0; off >>= 1) {
      pr0 += __shfl_down(pr0, off);
      pr1 += __shfl_down(pr1, off);
    }
    if ((tid & 63) == 0) { partial[tid >> 6][0] = pr0; partial[tid >> 6][1] = pr1; }
    __syncthreads();
    if (tid == 0) {
      const size_t o = (((size_t)b * 2 + half) * T_STEPS + t) * 2;
      oc[o + 0] = partial[0][0] + partial[1][0] + partial[2][0] + partial[3][0];
      oc[o + 1] = partial[0][1] + partial[1][1] + partial[2][1] + partial[3][1];
    }
    __syncthreads();
  }
}

// ---- LIF phase 2: output-layer membrane scan + spike count -----------------
__global__ __launch_bounds__(128) void lif_out_kernel(
    const float* __restrict__ oc, const float* __restrict__ bo,
    float* __restrict__ out) {
  const int b = threadIdx.x;
  float memo0 = 0.f, memo1 = 0.f, a0 = 0.f, a1 = 0.f;
  const float bo0 = bo[0], bo1 = bo[1];
  for (int t = 0; t < T_STEPS; ++t) {
    const size_t i0 = (((size_t)b * 2 + 0) * T_STEPS + t) * 2;
    const size_t i1 = (((size_t)b * 2 + 1) * T_STEPS + t) * 2;
    float o0 = oc[i0] + oc[i1] + bo0;
    float o1 = oc[i0 + 1] + oc[i1 + 1] + bo1;
    float ro0 = memo0 > 1.0f ? 1.0f : 0.0f;
    float ro1 = memo1 > 1.0f ? 1.0f : 0.0f;
    memo0 = 0.9f * memo0 + o0 - ro0;
    memo1 = 0.9f * memo1 + o1 - ro1;
    a0 += memo0 > 1.0f ? 1.0f : 0.0f;
    a1 += memo1 > 1.0f ? 1.0f : 0.0f;
  }
  out[b * 2 + 0] = a0;
  out[b * 2 + 1] = a1;
}

extern "C" void kernel_launch(void* const* d_in, const int* in_sizes, int n_in,
                              void* d_out, int out_size, void* d_ws, size_t ws_size,
                              hipStream_t stream) {
  const float* x  = (const float*)d_in[0];
  const float* W1 = (const float*)d_in[1];
  const float* b1 = (const float*)d_in[2];
  const float* Wo = (const float*)d_in[3];
  const float* bo = (const float*)d_in[4];
  float* out = (float*)d_out;

  const size_t part_bytes = PART_STRIDE * 4;                 // 27.26 MB
  const size_t a2_bytes = (size_t)13 * KT * 32768;           // 163.6 MB
  const size_t b2_bytes = (size_t)8 * KT * 32768;            // 100.7 MB
  const size_t oc_bytes = (size_t)128 * 2 * T_STEPS * 2 * 4; // 51.2 KB
  char* ws = (char*)d_ws;
  float* parts = (float*)ws;

  if (ws_size >= 2 * part_bytes + a2_bytes + b2_bytes + oc_bytes) {
    char* A2 = ws + 2 * part_bytes;
    char* B2 = A2 + a2_bytes;
    float* oc = (float*)(B2 + b2_bytes);
    conv_x_kernel<<<2048, 256, 0, stream>>>(x, A2);
    conv_w_kernel<<<2048, 256, 0, stream>>>(W1, B2);
    gemm_tile_kernel<<<208, 512, 0, stream>>>(A2, B2, parts);
    lif_hidden_kernel<<<256, 256, 0, stream>>>(parts, b1, Wo, oc, 1);
    lif_out_kernel<<<1, 128, 0, stream>>>(oc, bo, out);
  } else {
    float* oc = (float*)(ws + part_bytes);
    dim3 grid(25, 16);
    gemm_h_kernel<<<grid, 256, 0, stream>>>(x, W1, b1, (float*)ws);
    lif_hidden_kernel<<<256, 256, 0, stream>>>((const float*)ws, b1, Wo, oc, 0);
    lif_out_kernel<<<1, 128, 0, stream>>>(oc, bo, out);
  }
}